// Round 1
// baseline (434.558 us; speedup 1.0000x reference)
//
#include <hip/hip_runtime.h>

// GroupedConv2d: G=8 groups, each gathers 32 channels (permutation of 256),
// 3x3 conv pad=1 to J=64 outputs. x[16,256,56,56] fp32 -> out[16,512,56,56] fp32.
//
// Block = (g, b, 2-row x 56-col tile). 256 threads = 4 pixel-groups(pg) x 64 j,
// tid = pg*64 + j  (wave = fixed pg -> LDS x reads are wave-uniform broadcasts).
// LDS: xs[32][4][58] fp32 staged once/block + double-buffered per-c weights.

#define NG 8
#define CPER 32
#define CIN 256
#define NJ 64
#define NB 16
#define NH 56
#define NW 56

#define XS_ELEMS (32 * 4 * 58)   // 7424 floats
#define WBUF_ELEMS (NJ * 9)      // 576 floats per buffer

__global__ __launch_bounds__(256, 4)
void gconv2d_kernel(const float* __restrict__ x,
                    const float* __restrict__ w,
                    const float* __restrict__ bias,
                    const int* __restrict__ arr,
                    float* __restrict__ out) {
    __shared__ float smem[XS_ELEMS + 2 * WBUF_ELEMS];
    float* xs = smem;                    // [c][ir][colp], stride 58, colp = col+1
    float* wbuf = smem + XS_ELEMS;       // [2][576]

    const int tid  = threadIdx.x;
    const int row0 = blockIdx.x * 2;     // first output row of tile
    const int b    = blockIdx.y;
    const int g    = blockIdx.z;
    const int j    = tid & 63;
    const int pg   = tid >> 6;
    const int c0   = pg * 14;            // first output col this thread owns

    // ---- stage x tile: 32 channels x 4 input rows x 58 cols (halo, zero-filled)
    for (int e = tid; e < XS_ELEMS; e += 256) {
        int c    = e / 232;              // 232 = 4*58
        int rem  = e - c * 232;
        int ir   = rem / 58;
        int colp = rem - ir * 58;
        int col  = colp - 1;
        int row  = row0 - 1 + ir;
        float v = 0.0f;
        if ((unsigned)col < (unsigned)NW && (unsigned)row < (unsigned)NH) {
            int ch = arr[g * CPER + c];
            v = x[((b * CIN + ch) * NH + row) * NW + col];
        }
        xs[(c * 4 + ir) * 58 + colp] = v;
    }
    // ---- stage weights for c=0 into wbuf[0]
    for (int e = tid; e < WBUF_ELEMS; e += 256) {
        int jj = e / 9;
        int t  = e - jj * 9;
        wbuf[e] = w[(g * NJ + jj) * (CPER * 9) + 0 * 9 + t];
    }
    __syncthreads();

    float acc[2][14];
    {
        float bv = bias[g * NJ + j];
        #pragma unroll
        for (int r = 0; r < 2; ++r)
            #pragma unroll
            for (int col = 0; col < 14; ++col)
                acc[r][col] = bv;
    }

    for (int c = 0; c < CPER; ++c) {
        const int buf = c & 1;
        // prefetch next c's weights into the other buffer
        if (c + 1 < CPER) {
            for (int e = tid; e < WBUF_ELEMS; e += 256) {
                int jj = e / 9;
                int t  = e - jj * 9;
                wbuf[(buf ^ 1) * WBUF_ELEMS + e] =
                    w[(g * NJ + jj) * (CPER * 9) + (c + 1) * 9 + t];
            }
        }

        float wv[9];
        #pragma unroll
        for (int t = 0; t < 9; ++t) wv[t] = wbuf[buf * WBUF_ELEMS + j * 9 + t];

        const float* xc = xs + c * 232;
        #pragma unroll
        for (int ir = 0; ir < 4; ++ir) {
            float xr[16];
            #pragma unroll
            for (int t = 0; t < 16; ++t) xr[t] = xc[ir * 58 + c0 + t];
            // contributions: output row r gets kh = ir - r (input row = out row + kh - 1)
            #pragma unroll
            for (int r = 0; r < 2; ++r) {
                const int kh = ir - r;
                if (kh >= 0 && kh < 3) {
                    #pragma unroll
                    for (int col = 0; col < 14; ++col) {
                        acc[r][col] += xr[col]     * wv[kh * 3 + 0]
                                     + xr[col + 1] * wv[kh * 3 + 1]
                                     + xr[col + 2] * wv[kh * 3 + 2];
                    }
                }
            }
        }
        __syncthreads();   // weight dbuf handoff (also covers final xs reuse below)
    }

    // ---- epilogue: stage through LDS (stride 113 = conflict-free) for coalesced stores
    #pragma unroll
    for (int r = 0; r < 2; ++r)
        #pragma unroll
        for (int col = 0; col < 14; ++col)
            smem[j * 113 + r * 56 + c0 + col] = acc[r][col];
    __syncthreads();

    // 7168 outputs: out[b][g*64+jj][row0 + rem/56][rem%56]
    const long long obase = ((long long)(b * (NG * NJ) + g * NJ) * NH + row0) * NW;
    for (int e = tid; e < NJ * 2 * NW; e += 256) {
        int jj  = e / 112;
        int rem = e - jj * 112;          // r*56 + col
        out[obase + (long long)jj * (NH * NW) + rem] = smem[jj * 113 + rem];
    }
}

extern "C" void kernel_launch(void* const* d_in, const int* in_sizes, int n_in,
                              void* d_out, int out_size, void* d_ws, size_t ws_size,
                              hipStream_t stream) {
    const float* x    = (const float*)d_in[0];
    const float* wght = (const float*)d_in[1];
    const float* bias = (const float*)d_in[2];
    const int*   arr  = (const int*)d_in[3];
    float* out = (float*)d_out;

    dim3 grid(NH / 2, NB, NG);   // 28 x 16 x 8 = 3584 blocks
    gconv2d_kernel<<<grid, 256, 0, stream>>>(x, wght, bias, arr, out);
}

// Round 3
// 202.326 us; speedup vs baseline: 2.1478x; 2.1478x over previous
//
#include <hip/hip_runtime.h>

// GroupedConv2d via bf16 MFMA implicit GEMM — single kernel, no workspace.
// G=8 groups x 32 gathered channels -> J=64, 3x3 pad=1.
// x[16,256,56,56] fp32 -> out[16,512,56,56] fp32.
//
// Block = (g, b, 4-row band). 224 pixels = 14 N-tiles of 16. 4 waves; wave jt
// owns j in [jt*16, jt*16+16). Each thread converts its own 72 fp32 weights
// to 9 bf16 A-frags in registers (weights are L2/L3-resident; no d_ws, no
// second kernel -> nothing can corrupt persistent state across launches).
// LDS x-tile [6 rows][58 colp] with pixel stride 40 shorts (80 B) -> every
// B-frag (8 ch bf16 = 16 B) is 16-B aligned: one ds_read_b128 per tap.
// Per (tile, tap): 1 ds_read_b128 + 1 mfma_f32_16x16x32_bf16 (K=32 channels).

#define NG 8
#define CPER 32
#define CIN 256
#define NJ 64
#define NB 16
#define NH 56
#define NW 56
#define PXSTRIDE 40              // shorts per LDS pixel (32 ch + 8 pad) = 80 B
#define XS_SHORTS (6 * 58 * PXSTRIDE)
#define XSW_ELEMS (16 * 6 * 58)  // channel-pair staging elements

typedef __attribute__((ext_vector_type(8))) short short8v;
typedef __attribute__((ext_vector_type(4))) float float4v;

__device__ __forceinline__ unsigned bf16rne(float f) {
    unsigned u = __float_as_uint(f);
    return (u + 0x7FFFu + ((u >> 16) & 1u)) >> 16;
}

__global__ __launch_bounds__(256, 4)
void gconv_mfma(const float* __restrict__ x,
                const float* __restrict__ w,
                const float* __restrict__ bias,
                const int* __restrict__ arr,
                float* __restrict__ out) {
    __shared__ __align__(16) unsigned short xs[XS_SHORTS];

    const int tid  = threadIdx.x;
    const int band = blockIdx.x;       // 0..13 -> rows r0..r0+3
    const int b    = blockIdx.y;
    const int g    = blockIdx.z;
    const int r0   = band * 4;
    const int lane = tid & 63;
    const int jt   = tid >> 6;         // wave id = j-tile
    const int n    = lane & 15;        // pixel-in-tile / j-in-tile
    const int kq   = lane >> 4;        // k-quarter (channels kq*8..kq*8+7)

    // ---- stage x tile: [6 rows][58 colp][32 ch] bf16, zero-filled halo ----
    for (int e = tid; e < XSW_ELEMS; e += 256) {
        int c2   = e / 348;            // 348 = 6*58; channel-pair index 0..15
        int rem  = e - c2 * 348;
        int row  = rem / 58;           // LDS row 0..5 = input row r0-1+row
        int colp = rem - row * 58;     // LDS col 0..57 = input col colp-1
        int grow = r0 - 1 + row;
        int gcol = colp - 1;
        unsigned pack = 0;
        if ((unsigned)grow < (unsigned)NH && (unsigned)gcol < (unsigned)NW) {
            int ch0 = arr[g * CPER + c2 * 2];
            int ch1 = arr[g * CPER + c2 * 2 + 1];
            float v0 = x[((b * CIN + ch0) * NH + grow) * NW + gcol];
            float v1 = x[((b * CIN + ch1) * NH + grow) * NW + gcol];
            pack = bf16rne(v0) | (bf16rne(v1) << 16);
        }
        *(unsigned*)(&xs[(row * 58 + colp) * PXSTRIDE + c2 * 2]) = pack;
    }

    // ---- A-fragments: convert this thread's 72 fp32 weights in-register ----
    // w layout [g][j][c][kh][kw]; thread needs j = jt*16+n, c = kq*8..kq*8+7,
    // tap t = 0..8: w[wbase + cc*9 + t].
    short8v A[9];
    {
        const float* wp = w + ((size_t)((g * NJ + jt * 16 + n) * CPER) + kq * 8) * 9;
        #pragma unroll
        for (int t = 0; t < 9; ++t) {
            short8v a;
            #pragma unroll
            for (int cc = 0; cc < 8; ++cc)
                a[cc] = (short)(unsigned short)bf16rne(wp[cc * 9 + t]);
            A[t] = a;
        }
    }
    // bias init (C/D row = kq*4 + i)
    float4v binit;
    #pragma unroll
    for (int i = 0; i < 4; ++i) binit[i] = bias[g * NJ + jt * 16 + kq * 4 + i];

    __syncthreads();

    // ---- 14 N-tiles of 16 pixels (flattened over the 4-row band) ----
    int rl = 0, col = n;               // per-lane (row-in-band, col) of pixel
    for (int t = 0; t < 14; ++t) {
        float4v acc = binit;
        const unsigned short* pb = xs + (rl * 58 + col) * PXSTRIDE + kq * 8;
        #pragma unroll
        for (int kh = 0; kh < 3; ++kh) {
            #pragma unroll
            for (int kw = 0; kw < 3; ++kw) {
                short8v bv = *(const short8v*)(pb + (kh * 58 + kw) * PXSTRIDE);
                acc = __builtin_amdgcn_mfma_f32_16x16x32_bf16(
                    A[kh * 3 + kw], bv, acc, 0, 0, 0);
            }
        }
        // store: C/D col = n (pixel), row = kq*4+i (j within jt)
        int ob = (((b * (NG * NJ) + g * NJ + jt * 16 + kq * 4) * NH
                   + (r0 + rl)) * NW) + col;
        #pragma unroll
        for (int i = 0; i < 4; ++i)
            out[ob + i * (NH * NW)] = acc[i];

        col += 16;
        if (col >= NW) { col -= NW; rl += 1; }
    }
}

extern "C" void kernel_launch(void* const* d_in, const int* in_sizes, int n_in,
                              void* d_out, int out_size, void* d_ws, size_t ws_size,
                              hipStream_t stream) {
    const float* x    = (const float*)d_in[0];
    const float* wght = (const float*)d_in[1];
    const float* bias = (const float*)d_in[2];
    const int*   arr  = (const int*)d_in[3];
    float* out = (float*)d_out;

    dim3 grid(14, NB, NG);   // 4-row bands x batch x group = 1792 blocks
    gconv_mfma<<<grid, 256, 0, stream>>>(x, wght, bias, arr, out);
}

// Round 4
// 184.525 us; speedup vs baseline: 2.3550x; 1.0965x over previous
//
#include <hip/hip_runtime.h>

// GroupedConv2d via bf16 MFMA implicit GEMM — band-pipelined double buffer.
// G=8 groups x 32 gathered channels -> J=64, 3x3 pad=1.
// x[16,256,56,56] fp32 -> out[16,512,56,56] fp32.
//
// Block = (g, b, chunk of 7 two-row bands). 4 waves; wave jt owns 16 j's.
// Pipeline per band: (A) issue next band's global loads into regs,
// (B) compute current band from LDS (7 16x16 pixel-tiles, 9 taps each,
// mfma_f32_16x16x32_bf16, tiles paired for 2 indep acc chains),
// (C) convert+write next band into other LDS buffer, 1 barrier.
// LDS pixel stride 40 shorts (80 B) -> B-frags 16-B aligned (ds_read_b128).
// Weights staged once/block via LDS (coalesced) into per-thread A-frags.

#define NG 8
#define CPER 32
#define CIN 256
#define NJ 64
#define NB 16
#define NH 56
#define NW 56
#define PXST 40                 // shorts per LDS pixel (32 ch + 8 pad) = 80 B
#define BUFSH (4 * 58 * PXST)   // 9280 shorts per band buffer
#define NPACK (16 * 4 * 58)     // 3712 channel-pair packs per band
#define NITER 15                // ceil(3712/256)
#define WEI_SH (9 * 2048)       // 18432 shorts (fits in the 2 band buffers)

typedef __attribute__((ext_vector_type(8))) short short8v;
typedef __attribute__((ext_vector_type(4))) float float4v;

__device__ __forceinline__ unsigned bf16rne(float f) {
    unsigned u = __float_as_uint(f);
    return (u + 0x7FFFu + ((u >> 16) & 1u)) >> 16;
}

__global__ __launch_bounds__(256, 2)
void gconv_mfma(const float* __restrict__ x,
                const float* __restrict__ w,
                const float* __restrict__ bias,
                const int* __restrict__ arr,
                float* __restrict__ out) {
    __shared__ __align__(16) unsigned short smem[2 * BUFSH];

    const int tid   = threadIdx.x;
    const int chunk = blockIdx.x;      // 0..3 -> bands [chunk*7, chunk*7+7)
    const int b     = blockIdx.y;
    const int g     = blockIdx.z;
    const int lane  = tid & 63;
    const int jt    = tid >> 6;        // wave id = j-tile
    const int n     = lane & 15;       // pixel-in-tile / j-in-tile
    const int kq    = lane >> 4;       // k-quarter (channels kq*8..kq*8+7)

    // ---- stage weights: coalesced global read -> LDS [tap][j*32+c] bf16 ----
    {
        const float* wg = w + (size_t)g * (NJ * CPER * 9);
        for (int e = tid; e < WEI_SH; e += 256) {
            int jc = e / 9, tap = e - jc * 9;
            smem[tap * 2048 + jc] = (unsigned short)bf16rne(wg[e]);
        }
    }
    __syncthreads();
    short8v A[9];
    {
        const unsigned short* wl = smem + (jt * 16 + n) * CPER + kq * 8;
        #pragma unroll
        for (int t = 0; t < 9; ++t) A[t] = *(const short8v*)(wl + t * 2048);
    }
    float4v binit;
    #pragma unroll
    for (int i = 0; i < 4; ++i) binit[i] = bias[g * NJ + jt * 16 + kq * 4 + i];
    __syncthreads();   // weight region now reusable as band buffers

    // ---- precompute staging descriptors (registers, loop fully unrolled) ----
    int pre0[NITER], pre1[NITER], meta[NITER];
    #pragma unroll
    for (int k = 0; k < NITER; ++k) {
        int e = tid + 256 * k;
        int act = e < NPACK;
        int c2 = e / 232;              // 232 = 4*58 pixels per channel-pair
        int rem = e - c2 * 232;
        int row = rem / 58;            // LDS row 0..3 = input row r0-1+row
        int colp = rem - row * 58;     // LDS col 0..57 = input col colp-1
        int ch0 = 0, ch1 = 0;
        if (act) { ch0 = arr[g * CPER + c2 * 2]; ch1 = arr[g * CPER + c2 * 2 + 1]; }
        pre0[k] = ch0 * (NH * NW) + (row - 1) * NW + (colp - 1);
        pre1[k] = ch1 * (NH * NW) + (row - 1) * NW + (colp - 1);
        int cv = act && ((unsigned)(colp - 1) < NW);
        meta[k] = ((row * 58 + colp) * PXST + c2 * 2) | (row << 14) | (cv << 16) | (act << 17);
    }
    const float* xb = x + (size_t)b * (CIN * NH * NW);

    float f0[NITER], f1[NITER];
    int r0 = chunk * 14;               // output row base of this chunk's band 0

    // ---- prolog: stage band 0 into buffer 0 ----
    {
        int roff = r0 * NW;
        #pragma unroll
        for (int k = 0; k < NITER; ++k) {
            int row = (meta[k] >> 14) & 3;
            int v = ((meta[k] >> 16) & 1) && ((unsigned)(r0 + row - 1) < NH);
            f0[k] = v ? xb[pre0[k] + roff] : 0.0f;
            f1[k] = v ? xb[pre1[k] + roff] : 0.0f;
        }
        #pragma unroll
        for (int k = 0; k < NITER; ++k) {
            if ((meta[k] >> 17) & 1)
                *(unsigned*)(&smem[meta[k] & 0x3FFF]) =
                    bf16rne(f0[k]) | (bf16rne(f1[k]) << 16);
        }
    }
    __syncthreads();

    // ---- pipelined band loop ----
    for (int bd = 0; bd < 7; ++bd) {
        // phase A: issue next band's loads (no wait until phase C)
        if (bd < 6) {
            int r1 = r0 + 2, roff = r1 * NW;
            #pragma unroll
            for (int k = 0; k < NITER; ++k) {
                int row = (meta[k] >> 14) & 3;
                int v = ((meta[k] >> 16) & 1) && ((unsigned)(r1 + row - 1) < NH);
                f0[k] = v ? xb[pre0[k] + roff] : 0.0f;
                f1[k] = v ? xb[pre1[k] + roff] : 0.0f;
            }
        }
        // phase B: compute current band from buf[bd&1]
        {
            const unsigned short* buf = smem + (bd & 1) * BUFSH;
            const int obase = ((b * (NG * NJ) + g * NJ + jt * 16 + kq * 4) * NH + r0) * NW;
            int rl = 0, col = n;
            #pragma unroll
            for (int tp = 0; tp < 3; ++tp) {
                int rlA = rl, colA = col; col += 16; if (col >= NW) { col -= NW; ++rl; }
                int rlB = rl, colB = col; col += 16; if (col >= NW) { col -= NW; ++rl; }
                const unsigned short* pA = buf + (rlA * 58 + colA) * PXST + kq * 8;
                const unsigned short* pB = buf + (rlB * 58 + colB) * PXST + kq * 8;
                float4v a0 = binit, a1 = binit;
                #pragma unroll
                for (int kh = 0; kh < 3; ++kh)
                    #pragma unroll
                    for (int kw = 0; kw < 3; ++kw) {
                        short8v b0 = *(const short8v*)(pA + (kh * 58 + kw) * PXST);
                        short8v b1 = *(const short8v*)(pB + (kh * 58 + kw) * PXST);
                        a0 = __builtin_amdgcn_mfma_f32_16x16x32_bf16(A[kh * 3 + kw], b0, a0, 0, 0, 0);
                        a1 = __builtin_amdgcn_mfma_f32_16x16x32_bf16(A[kh * 3 + kw], b1, a1, 0, 0, 0);
                    }
                int obA = obase + rlA * NW + colA;
                int obB = obase + rlB * NW + colB;
                #pragma unroll
                for (int i = 0; i < 4; ++i) {
                    out[obA + i * (NH * NW)] = a0[i];
                    out[obB + i * (NH * NW)] = a1[i];
                }
            }
            // tile 6 (single)
            const unsigned short* pA = buf + (rl * 58 + col) * PXST + kq * 8;
            float4v a0 = binit;
            #pragma unroll
            for (int kh = 0; kh < 3; ++kh)
                #pragma unroll
                for (int kw = 0; kw < 3; ++kw) {
                    short8v b0 = *(const short8v*)(pA + (kh * 58 + kw) * PXST);
                    a0 = __builtin_amdgcn_mfma_f32_16x16x32_bf16(A[kh * 3 + kw], b0, a0, 0, 0, 0);
                }
            int obA = obase + rl * NW + col;
            #pragma unroll
            for (int i = 0; i < 4; ++i) out[obA + i * (NH * NW)] = a0[i];
        }
        // phase C: convert + write next band into the other buffer
        if (bd < 6) {
            unsigned short* dst = smem + ((bd + 1) & 1) * BUFSH;
            #pragma unroll
            for (int k = 0; k < NITER; ++k) {
                if ((meta[k] >> 17) & 1)
                    *(unsigned*)(&dst[meta[k] & 0x3FFF]) =
                        bf16rne(f0[k]) | (bf16rne(f1[k]) << 16);
            }
            r0 += 2;
            __syncthreads();
        }
    }
}

extern "C" void kernel_launch(void* const* d_in, const int* in_sizes, int n_in,
                              void* d_out, int out_size, void* d_ws, size_t ws_size,
                              hipStream_t stream) {
    const float* x    = (const float*)d_in[0];
    const float* wght = (const float*)d_in[1];
    const float* bias = (const float*)d_in[2];
    const int*   arr  = (const int*)d_in[3];
    float* out = (float*)d_out;

    dim3 grid(4, NB, NG);   // 4 chunks x batch x group = 512 blocks (2/CU)
    gconv_mfma<<<grid, 256, 0, stream>>>(x, wght, bias, arr, out);
}